// Round 1
// baseline (127.013 us; speedup 1.0000x reference)
//
#include <hip/hip_runtime.h>
#include <math.h>

// PatchNorm forward (training mode Welford update + normalize).
// Shapes (fixed by the reference setup):
//   patches (B=32, S=1024, D=768) fp32, N = B*S = 32768 tokens
//   pos_h/pos_w/key_pad_mask (B,S) int32
//   n (32,32) fp32, mean/m2 (32,32,256) fp32
//   out (B,S,768) fp32
#define EPSF 1e-6f

static constexpr int W_GRID = 32;  // grid width (pf = pos_h*W + pos_w)
static constexpr int P2     = 256; // patch_res^2
static constexpr int CCH    = 3;   // channels
static constexpr int DDIM   = 768; // C*P2

// ---- kernel 1: channel-mean xbar + per-token count scatter -----------------
__global__ void k_stage1(const float* __restrict__ patches,
                         const int* __restrict__ pos_h,
                         const int* __restrict__ pos_w,
                         const int* __restrict__ mask,
                         float* __restrict__ xbar,
                         float* __restrict__ counts,
                         int use_xbar) {
    const int i = blockIdx.x;      // token
    const int p = threadIdx.x;     // 0..255
    if (use_xbar) {
        const float* pp = patches + (size_t)i * DDIM;
        float v = (pp[p] + pp[P2 + p] + pp[2 * P2 + p]) * (1.0f / 3.0f);
        xbar[(size_t)i * P2 + p] = v;
    }
    if (p == 0 && mask[i] == 0) {
        int g = pos_h[i] * W_GRID + pos_w[i];
        atomicAdd(&counts[g], 1.0f);
    }
}

// ---- kernel 2: n_new = n + counts ------------------------------------------
__global__ void k_nnew(const float* __restrict__ n_old,
                       const float* __restrict__ counts,
                       float* __restrict__ n_new, int HW) {
    int g = blockIdx.x * blockDim.x + threadIdx.x;
    if (g < HW) n_new[g] = n_old[g] + counts[g];
}

// ---- kernel 3: scatter sum of delta / n_g ----------------------------------
__global__ void k_delta(const float* __restrict__ patches,
                        const float* __restrict__ xbar,
                        const int* __restrict__ pos_h,
                        const int* __restrict__ pos_w,
                        const int* __restrict__ mask,
                        const float* __restrict__ mean_old,
                        const float* __restrict__ n_new,
                        float* __restrict__ sum_mean,
                        int use_xbar) {
    const int i = blockIdx.x;
    if (mask[i] != 0) return;               // w==0: contributes nothing
    const int p = threadIdx.x;
    const int g = pos_h[i] * W_GRID + pos_w[i];
    float xb;
    if (use_xbar) {
        xb = xbar[(size_t)i * P2 + p];
    } else {
        const float* pp = patches + (size_t)i * DDIM;
        xb = (pp[p] + pp[P2 + p] + pp[2 * P2 + p]) * (1.0f / 3.0f);
    }
    float ng = n_new[g];
    ng = ng < 1.0f ? 1.0f : ng;
    float dlt = xb - mean_old[g * P2 + p];
    atomicAdd(&sum_mean[g * P2 + p], dlt / ng);
}

// ---- kernel 4: mean_new = mean + sum ---------------------------------------
__global__ void k_meannew(const float* __restrict__ mean_old,
                          const float* __restrict__ sum_mean,
                          float* __restrict__ mean_new, int HWP2) {
    int j = blockIdx.x * blockDim.x + threadIdx.x;
    if (j < HWP2) mean_new[j] = mean_old[j] + sum_mean[j];
}

// ---- kernel 5: scatter sum of delta*delta2 ---------------------------------
__global__ void k_m2(const float* __restrict__ patches,
                     const float* __restrict__ xbar,
                     const int* __restrict__ pos_h,
                     const int* __restrict__ pos_w,
                     const int* __restrict__ mask,
                     const float* __restrict__ mean_old,
                     const float* __restrict__ mean_new,
                     float* __restrict__ sum_m2,
                     int use_xbar) {
    const int i = blockIdx.x;
    if (mask[i] != 0) return;
    const int p = threadIdx.x;
    const int g = pos_h[i] * W_GRID + pos_w[i];
    float xb;
    if (use_xbar) {
        xb = xbar[(size_t)i * P2 + p];
    } else {
        const float* pp = patches + (size_t)i * DDIM;
        xb = (pp[p] + pp[P2 + p] + pp[2 * P2 + p]) * (1.0f / 3.0f);
    }
    float d1 = xb - mean_old[g * P2 + p];
    float d2 = xb - mean_new[g * P2 + p];
    atomicAdd(&sum_m2[g * P2 + p], d1 * d2);
}

// ---- kernel 6: per-cell inv_std --------------------------------------------
__global__ void k_stats(const float* __restrict__ m2_old,
                        const float* __restrict__ sum_m2,
                        const float* __restrict__ n_new,
                        float* __restrict__ inv_std, int HWP2) {
    int j = blockIdx.x * blockDim.x + threadIdx.x;
    if (j >= HWP2) return;
    int g = j / P2;
    float nn = n_new[g];
    float m2n = m2_old[j] + sum_m2[j];
    float var = (nn < 2.0f) ? 1.0f : (m2n / fmaxf(nn, 1.0f));
    inv_std[j] = 1.0f / (sqrtf(var) + EPSF);
}

// ---- kernel 7: normalize ----------------------------------------------------
__global__ void k_norm(const float* __restrict__ patches,
                       const int* __restrict__ pos_h,
                       const int* __restrict__ pos_w,
                       const int* __restrict__ mask,
                       const float* __restrict__ mean_new,
                       const float* __restrict__ inv_std,
                       float* __restrict__ out) {
    const int i = blockIdx.x;
    const int p = threadIdx.x;
    const int g = pos_h[i] * W_GRID + pos_w[i];
    const float wv = (mask[i] == 0) ? 1.0f : 0.0f;
    const float m = mean_new[g * P2 + p];
    const float s = inv_std[g * P2 + p];
    const float* pp = patches + (size_t)i * DDIM;
    float* op = out + (size_t)i * DDIM;
#pragma unroll
    for (int c = 0; c < CCH; ++c) {
        op[c * P2 + p] = (pp[c * P2 + p] - m) * s * wv;
    }
}

extern "C" void kernel_launch(void* const* d_in, const int* in_sizes, int n_in,
                              void* d_out, int out_size, void* d_ws, size_t ws_size,
                              hipStream_t stream) {
    const float* patches = (const float*)d_in[0];
    const int*   pos_h   = (const int*)d_in[1];
    const int*   pos_w   = (const int*)d_in[2];
    const int*   mask    = (const int*)d_in[3];
    const float* n_old   = (const float*)d_in[4];
    const float* mean    = (const float*)d_in[5];
    const float* m2      = (const float*)d_in[6];
    float* out = (float*)d_out;

    const int N    = in_sizes[1];       // 32768 tokens
    const int HW   = in_sizes[4];       // 1024 grid cells
    const int HWP2 = in_sizes[5];       // 262144

    // workspace layout (floats):
    //   [counts HW][sum_mean HWP2][sum_m2 HWP2]  <- zeroed each call
    //   [n_new HW][mean_new HWP2][inv_std HWP2][xbar N*P2 (optional)]
    float* ws       = (float*)d_ws;
    float* counts   = ws;
    float* sum_mean = counts + HW;
    float* sum_m2   = sum_mean + HWP2;
    float* n_new    = sum_m2 + HWP2;
    float* mean_new = n_new + HW;
    float* inv_std  = mean_new + HWP2;
    float* xbar     = inv_std + HWP2;

    const size_t core_floats = (size_t)2 * HW + (size_t)4 * HWP2;
    const size_t xbar_floats = (size_t)N * P2;
    const int use_xbar = (ws_size >= (core_floats + xbar_floats) * sizeof(float)) ? 1 : 0;

    // zero the accumulators (counts + sum_mean + sum_m2 are contiguous)
    const size_t zero_bytes = ((size_t)HW + 2 * (size_t)HWP2) * sizeof(float);
    hipMemsetAsync(d_ws, 0, zero_bytes, stream);

    k_stage1<<<N, P2, 0, stream>>>(patches, pos_h, pos_w, mask, xbar, counts, use_xbar);
    k_nnew<<<(HW + 255) / 256, 256, 0, stream>>>(n_old, counts, n_new, HW);
    k_delta<<<N, P2, 0, stream>>>(patches, xbar, pos_h, pos_w, mask, mean, n_new,
                                  sum_mean, use_xbar);
    k_meannew<<<(HWP2 + 255) / 256, 256, 0, stream>>>(mean, sum_mean, mean_new, HWP2);
    k_m2<<<N, P2, 0, stream>>>(patches, xbar, pos_h, pos_w, mask, mean, mean_new,
                               sum_m2, use_xbar);
    k_stats<<<(HWP2 + 255) / 256, 256, 0, stream>>>(m2, sum_m2, n_new, inv_std, HWP2);
    k_norm<<<N, P2, 0, stream>>>(patches, pos_h, pos_w, mask, mean_new, inv_std, out);
}